// Round 3
// baseline (191.530 us; speedup 1.0000x reference)
//
#include <hip/hip_runtime.h>

// PopulationAttention: out = (Q K^T / sqrt(64)) @ (V * x)
// No softmax => associativity: out = Q @ M, M = K^T @ (V*x) / 8  (64x64 per head)
// B=4, H=16, N=2048, D=64  -> BH=64 batched heads.

#define BH 64
#define NROWS 2048
#define DIM 64

// ---- Stage A: partial[bh][chunk] = sum K^T (V*x); last block per head reduces to M ----
__global__ __launch_bounds__(256) void popattn_kv(
    const float* __restrict__ K, const float* __restrict__ V,
    const float* __restrict__ x, float* __restrict__ partial,
    float* __restrict__ M, int* __restrict__ counters, int nchunk) {
  const int ch = blockIdx.x;
  const int bh = blockIdx.y;
  const int rows = NROWS / nchunk;
  const int m0base = ch * rows;
  const float* Kp = K + (size_t)bh * (NROWS * DIM);
  const float* Vp = V + (size_t)bh * (NROWS * DIM);
  const float* xp = x + (size_t)(bh >> 4) * NROWS;  // x is [B,1,N,1], b = bh/16

  __shared__ float sK[32][DIM];  // 8 KB
  __shared__ float sV[32][DIM];  // 8 KB

  const int t = threadIdx.x;
  const int lr = t >> 4;          // load row 0..15 (and +16)
  const int lc = (t & 15) << 2;   // load col (float4)
  const int ti = (t >> 4) << 2;   // 4x4 tile row base
  const int tj = (t & 15) << 2;   // 4x4 tile col base

  float acc[4][4];
#pragma unroll
  for (int i = 0; i < 4; ++i)
#pragma unroll
    for (int j = 0; j < 4; ++j) acc[i][j] = 0.f;

  for (int m0 = m0base; m0 < m0base + rows; m0 += 32) {
    const float4 kv0 = *(const float4*)(Kp + (size_t)(m0 + lr) * DIM + lc);
    const float4 kv1 = *(const float4*)(Kp + (size_t)(m0 + 16 + lr) * DIM + lc);
    const float4 vv0 = *(const float4*)(Vp + (size_t)(m0 + lr) * DIM + lc);
    const float4 vv1 = *(const float4*)(Vp + (size_t)(m0 + 16 + lr) * DIM + lc);
    const float xv0 = xp[m0 + lr];
    const float xv1 = xp[m0 + 16 + lr];
    __syncthreads();  // protect previous iteration's reads
    *(float4*)&sK[lr][lc] = kv0;
    *(float4*)&sK[lr + 16][lc] = kv1;
    float4 vs;
    vs.x = vv0.x * xv0; vs.y = vv0.y * xv0; vs.z = vv0.z * xv0; vs.w = vv0.w * xv0;
    *(float4*)&sV[lr][lc] = vs;
    vs.x = vv1.x * xv1; vs.y = vv1.y * xv1; vs.z = vv1.z * xv1; vs.w = vv1.w * xv1;
    *(float4*)&sV[lr + 16][lc] = vs;
    __syncthreads();
#pragma unroll
    for (int mm = 0; mm < 32; ++mm) {
      const float4 ka = *(const float4*)&sK[mm][ti];
      const float4 va = *(const float4*)&sV[mm][tj];
      const float kk[4] = {ka.x, ka.y, ka.z, ka.w};
      const float vw[4] = {va.x, va.y, va.z, va.w};
#pragma unroll
      for (int ii = 0; ii < 4; ++ii)
#pragma unroll
        for (int jj = 0; jj < 4; ++jj) acc[ii][jj] += kk[ii] * vw[jj];
    }
  }

  float* Pp = partial + ((size_t)bh * nchunk + ch) * (DIM * DIM);
#pragma unroll
  for (int ii = 0; ii < 4; ++ii) {
    float4 o;
    o.x = acc[ii][0]; o.y = acc[ii][1]; o.z = acc[ii][2]; o.w = acc[ii][3];
    *(float4*)(Pp + (size_t)(ti + ii) * DIM + tj) = o;
  }

  // ---- deterministic last-block fixup: reduce partials -> M (fixed order) ----
  __threadfence();  // make this block's partial visible device-wide
  __shared__ int sIsLast;
  if (t == 0) {
    const int old = atomicAdd(&counters[bh], 1);
    sIsLast = (old == nchunk - 1) ? 1 : 0;
  }
  __syncthreads();
  if (sIsLast) {
    __threadfence();  // acquire: see all other blocks' partials
    const float* P0 = partial + (size_t)bh * nchunk * (DIM * DIM);
    float* Mp = M + (size_t)bh * (DIM * DIM);
#pragma unroll
    for (int e = 0; e < 4; ++e) {
      const int off = e * 1024 + t * 4;
      float sx = 0.f, sy = 0.f, sz = 0.f, sw = 0.f;
      for (int c = 0; c < nchunk; ++c) {  // fixed order -> bitwise deterministic
        const float4 p = *(const float4*)(P0 + (size_t)c * (DIM * DIM) + off);
        sx += p.x; sy += p.y; sz += p.z; sw += p.w;
      }
      float4 o;
      o.x = sx * 0.125f; o.y = sy * 0.125f; o.z = sz * 0.125f; o.w = sw * 0.125f;
      *(float4*)(Mp + off) = o;
    }
  }
}

// ---- Stage B: out[bh] = Q[bh] @ M[bh].  128 rows/block, per-thread 4x8 tile ----
__global__ __launch_bounds__(256) void popattn_qm(
    const float* __restrict__ Q, const float* __restrict__ M,
    float* __restrict__ out) {
  const int ch = blockIdx.x;  // 0..15
  const int bh = blockIdx.y;
  const int row0 = ch * 128;
  const float* Qp = Q + (size_t)bh * (NROWS * DIM) + (size_t)row0 * DIM;
  float* Op = out + (size_t)bh * (NROWS * DIM) + (size_t)row0 * DIM;

  __shared__ float sM[DIM * DIM];  // 16 KB

  const int t = threadIdx.x;
  {
    const float* Mp = M + (size_t)bh * (DIM * DIM);
#pragma unroll
    for (int i = 0; i < 4; ++i) {
      const int off = i * 1024 + t * 4;
      *(float4*)&sM[off] = *(const float4*)(Mp + off);
    }
  }
  __syncthreads();

  const int r = t >> 3;         // rows r, r+32, r+64, r+96
  const int c4 = (t & 7) * 4;   // cols c4..c4+3 and c4+32..c4+35

  float acc[4][8];
#pragma unroll
  for (int rr = 0; rr < 4; ++rr)
#pragma unroll
    for (int jj = 0; jj < 8; ++jj) acc[rr][jj] = 0.f;

#pragma unroll
  for (int kg = 0; kg < 16; ++kg) {
    float4 qv[4];
#pragma unroll
    for (int rr = 0; rr < 4; ++rr)
      qv[rr] = *(const float4*)(Qp + (size_t)(r + 32 * rr) * DIM + kg * 4);
#pragma unroll
    for (int dk = 0; dk < 4; ++dk) {
      const int k = kg * 4 + dk;
      const float4 m0 = *(const float4*)&sM[k * DIM + c4];
      const float4 m1 = *(const float4*)&sM[k * DIM + c4 + 32];
      const float mm[8] = {m0.x, m0.y, m0.z, m0.w, m1.x, m1.y, m1.z, m1.w};
#pragma unroll
      for (int rr = 0; rr < 4; ++rr) {
        const float q = (dk == 0) ? qv[rr].x : (dk == 1) ? qv[rr].y
                       : (dk == 2) ? qv[rr].z : qv[rr].w;
#pragma unroll
        for (int jj = 0; jj < 8; ++jj) acc[rr][jj] += q * mm[jj];
      }
    }
  }

#pragma unroll
  for (int rr = 0; rr < 4; ++rr) {
    float4 o;
    o.x = acc[rr][0]; o.y = acc[rr][1]; o.z = acc[rr][2]; o.w = acc[rr][3];
    *(float4*)(Op + (size_t)(r + 32 * rr) * DIM + c4) = o;
    o.x = acc[rr][4]; o.y = acc[rr][5]; o.z = acc[rr][6]; o.w = acc[rr][7];
    *(float4*)(Op + (size_t)(r + 32 * rr) * DIM + c4 + 32) = o;
  }
}

extern "C" void kernel_launch(void* const* d_in, const int* in_sizes, int n_in,
                              void* d_out, int out_size, void* d_ws, size_t ws_size,
                              hipStream_t stream) {
  const float* Q = (const float*)d_in[0];
  const float* K = (const float*)d_in[1];
  const float* V = (const float*)d_in[2];
  const float* x = (const float*)d_in[3];
  float* out = (float*)d_out;
  float* partial = (float*)d_ws;

  int nchunk = 16;
  while (nchunk > 1 &&
         ((size_t)BH * nchunk * DIM * DIM + (size_t)BH * DIM * DIM) * sizeof(float) +
                 BH * sizeof(int) > ws_size)
    nchunk >>= 1;
  float* Mbuf = partial + (size_t)BH * nchunk * DIM * DIM;
  int* counters = (int*)(Mbuf + (size_t)BH * DIM * DIM);

  // zero the per-head arrival counters (graph-capture-safe, 256 B)
  hipMemsetAsync(counters, 0, BH * sizeof(int), stream);

  dim3 blk(256);
  popattn_kv<<<dim3(nchunk, BH), blk, 0, stream>>>(K, V, x, partial, Mbuf,
                                                   counters, nchunk);
  popattn_qm<<<dim3(NROWS / 128, BH), blk, 0, stream>>>(Q, Mbuf, out);
}

// Round 4
// 53.571 us; speedup vs baseline: 3.5753x; 3.5753x over previous
//
#include <hip/hip_runtime.h>

// PopulationAttention: out = (Q K^T / sqrt(64)) @ (V * x)
// No softmax => associativity: out = Q @ M, M = K^T @ (V*x) / 8  (64x64 per head)
// B=4, H=16, N=2048, D=64  -> BH=64 batched heads.
// 3 kernels; coherence via kernel boundaries (NO device-scope fences — R2's
// per-block __threadfence caused a 4.3x regression from L2 writeback storms).

#define BH 64
#define NROWS 2048
#define DIM 64

// ---- Stage A: partial[bh][chunk] = sum_{m in chunk} K[m]^T (V[m]*x[m]) ----
// 128 rows/block. Each wave (=slice) owns 8 of each 32 staged rows with an
// 8x8 per-thread register tile (1 B LDS per FMA), then a fixed-order
// sequential cross-wave reduction in LDS (deterministic).
__global__ __launch_bounds__(256) void popattn_kv(
    const float* __restrict__ K, const float* __restrict__ V,
    const float* __restrict__ x, float* __restrict__ partial, int nchunk) {
  const int ch = blockIdx.x;
  const int bh = blockIdx.y;
  const int rows = NROWS / nchunk;  // 128
  const int m0base = ch * rows;
  const float* Kp = K + (size_t)bh * (NROWS * DIM);
  const float* Vp = V + (size_t)bh * (NROWS * DIM);
  const float* xp = x + (size_t)(bh >> 4) * NROWS;  // x is [B,1,N,1], b = bh/16

  __shared__ float smem[4096];  // 16 KB: sK[32][64] | sV[32][64], reused for reduce
  float (*sK)[DIM] = (float(*)[DIM])smem;
  float (*sV)[DIM] = (float(*)[DIM])(smem + 2048);

  const int t = threadIdx.x;
  const int lr = t >> 4;          // staging row 0..15 (and +16)
  const int lc = (t & 15) << 2;   // staging col (float4)
  const int wv = t >> 6;          // wave id == row-slice id (0..3)
  const int l = t & 63;
  const int ti = (l >> 3) << 3;   // 8x8 tile row base
  const int tj = (l & 7) << 3;    // 8x8 tile col base

  float acc[8][8];
#pragma unroll
  for (int i = 0; i < 8; ++i)
#pragma unroll
    for (int j = 0; j < 8; ++j) acc[i][j] = 0.f;

  for (int m0 = m0base; m0 < m0base + rows; m0 += 32) {
    const float4 kv0 = *(const float4*)(Kp + (size_t)(m0 + lr) * DIM + lc);
    const float4 kv1 = *(const float4*)(Kp + (size_t)(m0 + 16 + lr) * DIM + lc);
    const float4 vv0 = *(const float4*)(Vp + (size_t)(m0 + lr) * DIM + lc);
    const float4 vv1 = *(const float4*)(Vp + (size_t)(m0 + 16 + lr) * DIM + lc);
    const float xv0 = xp[m0 + lr];
    const float xv1 = xp[m0 + 16 + lr];
    __syncthreads();  // protect previous iteration's reads
    *(float4*)&sK[lr][lc] = kv0;
    *(float4*)&sK[lr + 16][lc] = kv1;
    float4 vs;
    vs.x = vv0.x * xv0; vs.y = vv0.y * xv0; vs.z = vv0.z * xv0; vs.w = vv0.w * xv0;
    *(float4*)&sV[lr][lc] = vs;
    vs.x = vv1.x * xv1; vs.y = vv1.y * xv1; vs.z = vv1.z * xv1; vs.w = vv1.w * xv1;
    *(float4*)&sV[lr + 16][lc] = vs;
    __syncthreads();
#pragma unroll
    for (int mm = 0; mm < 8; ++mm) {
      const int row = wv * 8 + mm;  // wave-private slice: no divergence
      const float4 ka0 = *(const float4*)&sK[row][ti];
      const float4 ka1 = *(const float4*)&sK[row][ti + 4];
      const float4 vb0 = *(const float4*)&sV[row][tj];
      const float4 vb1 = *(const float4*)&sV[row][tj + 4];
      const float kk[8] = {ka0.x, ka0.y, ka0.z, ka0.w, ka1.x, ka1.y, ka1.z, ka1.w};
      const float vw[8] = {vb0.x, vb0.y, vb0.z, vb0.w, vb1.x, vb1.y, vb1.z, vb1.w};
#pragma unroll
      for (int ii = 0; ii < 8; ++ii)
#pragma unroll
        for (int jj = 0; jj < 8; ++jj) acc[ii][jj] += kk[ii] * vw[jj];
    }
  }

  // ---- cross-wave reduce into smem, fixed order s=0,1,2,3 (deterministic) ----
  __syncthreads();
#pragma unroll 1
  for (int s2 = 0; s2 < 4; ++s2) {
    if (wv == s2) {
#pragma unroll
      for (int ii = 0; ii < 8; ++ii) {
        float* dst = &smem[(ti + ii) * DIM + tj];
        if (s2 == 0) {
          float4 o;
          o.x = acc[ii][0]; o.y = acc[ii][1]; o.z = acc[ii][2]; o.w = acc[ii][3];
          *(float4*)dst = o;
          o.x = acc[ii][4]; o.y = acc[ii][5]; o.z = acc[ii][6]; o.w = acc[ii][7];
          *(float4*)(dst + 4) = o;
        } else {
          float4 a = *(float4*)dst;
          a.x += acc[ii][0]; a.y += acc[ii][1]; a.z += acc[ii][2]; a.w += acc[ii][3];
          *(float4*)dst = a;
          a = *(float4*)(dst + 4);
          a.x += acc[ii][4]; a.y += acc[ii][5]; a.z += acc[ii][6]; a.w += acc[ii][7];
          *(float4*)(dst + 4) = a;
        }
      }
    }
    __syncthreads();
  }

  // write 64x64 partial, coalesced
  float* Pp = partial + ((size_t)bh * nchunk + ch) * (DIM * DIM);
#pragma unroll
  for (int i = 0; i < 4; ++i) {
    const int idx = (t + 256 * i) * 4;
    *(float4*)(Pp + idx) = *(const float4*)&smem[idx];
  }
}

// ---- Stage A2: M[bh] = (sum_c partial[bh][c]) * 0.125, fixed order ----
__global__ __launch_bounds__(256) void popattn_red(
    const float* __restrict__ partial, float* __restrict__ M, int nchunk) {
  const int e = blockIdx.x;   // 0..3 quarter of the 64x64 matrix
  const int bh = blockIdx.y;
  const int off = e * 1024 + threadIdx.x * 4;
  const float* Pp = partial + (size_t)bh * nchunk * (DIM * DIM);
  float sx = 0.f, sy = 0.f, sz = 0.f, sw = 0.f;
#pragma unroll 4
  for (int c = 0; c < nchunk; ++c) {
    const float4 p = *(const float4*)(Pp + (size_t)c * (DIM * DIM) + off);
    sx += p.x; sy += p.y; sz += p.z; sw += p.w;
  }
  float4 o;
  o.x = sx * 0.125f; o.y = sy * 0.125f; o.z = sz * 0.125f; o.w = sw * 0.125f;
  *(float4*)(M + (size_t)bh * (DIM * DIM) + off) = o;
}

// ---- Stage B: out[bh] = Q[bh] @ M[bh].  256 rows/block, per-thread 8x8 tile ----
__global__ __launch_bounds__(256) void popattn_qm(
    const float* __restrict__ Q, const float* __restrict__ M,
    float* __restrict__ out) {
  const int ch = blockIdx.x;  // 0..7
  const int bh = blockIdx.y;
  const int row0 = ch * 256;
  const float* Qp = Q + (size_t)bh * (NROWS * DIM) + (size_t)row0 * DIM;
  float* Op = out + (size_t)bh * (NROWS * DIM) + (size_t)row0 * DIM;

  __shared__ float sM[DIM * DIM];  // 16 KB

  const int t = threadIdx.x;
  {
    const float* Mp = M + (size_t)bh * (DIM * DIM);
#pragma unroll
    for (int i = 0; i < 4; ++i) {
      const int off = i * 1024 + t * 4;
      *(float4*)&sM[off] = *(const float4*)(Mp + off);
    }
  }
  __syncthreads();

  const int r = t >> 3;         // rows r + 32*rr, rr = 0..7
  const int c8 = (t & 7) * 8;   // cols c8..c8+7

  float acc[8][8];
#pragma unroll
  for (int rr = 0; rr < 8; ++rr)
#pragma unroll
    for (int jj = 0; jj < 8; ++jj) acc[rr][jj] = 0.f;

#pragma unroll 2
  for (int kg = 0; kg < 16; ++kg) {
    float4 qv[8];
#pragma unroll
    for (int rr = 0; rr < 8; ++rr)
      qv[rr] = *(const float4*)(Qp + (size_t)(r + 32 * rr) * DIM + kg * 4);
#pragma unroll
    for (int dk = 0; dk < 4; ++dk) {
      const int k = kg * 4 + dk;
      const float4 m0 = *(const float4*)&sM[k * DIM + c8];
      const float4 m1 = *(const float4*)&sM[k * DIM + c8 + 4];
      const float mm[8] = {m0.x, m0.y, m0.z, m0.w, m1.x, m1.y, m1.z, m1.w};
#pragma unroll
      for (int rr = 0; rr < 8; ++rr) {
        const float q = (dk == 0) ? qv[rr].x : (dk == 1) ? qv[rr].y
                       : (dk == 2) ? qv[rr].z : qv[rr].w;
#pragma unroll
        for (int jj = 0; jj < 8; ++jj) acc[rr][jj] += q * mm[jj];
      }
    }
  }

#pragma unroll
  for (int rr = 0; rr < 8; ++rr) {
    float4 o;
    o.x = acc[rr][0]; o.y = acc[rr][1]; o.z = acc[rr][2]; o.w = acc[rr][3];
    *(float4*)(Op + (size_t)(r + 32 * rr) * DIM + c8) = o;
    o.x = acc[rr][4]; o.y = acc[rr][5]; o.z = acc[rr][6]; o.w = acc[rr][7];
    *(float4*)(Op + (size_t)(r + 32 * rr) * DIM + c8 + 4) = o;
  }
}

extern "C" void kernel_launch(void* const* d_in, const int* in_sizes, int n_in,
                              void* d_out, int out_size, void* d_ws, size_t ws_size,
                              hipStream_t stream) {
  const float* Q = (const float*)d_in[0];
  const float* K = (const float*)d_in[1];
  const float* V = (const float*)d_in[2];
  const float* x = (const float*)d_in[3];
  float* out = (float*)d_out;
  float* partial = (float*)d_ws;

  int nchunk = 16;
  while (nchunk > 1 &&
         ((size_t)BH * nchunk * DIM * DIM + (size_t)BH * DIM * DIM) * sizeof(float) > ws_size)
    nchunk >>= 1;
  float* Mbuf = partial + (size_t)BH * nchunk * DIM * DIM;

  dim3 blk(256);
  popattn_kv<<<dim3(nchunk, BH), blk, 0, stream>>>(K, V, x, partial, nchunk);
  popattn_red<<<dim3(4, BH), blk, 0, stream>>>(partial, Mbuf, nchunk);
  popattn_qm<<<dim3(NROWS / 256, BH), blk, 0, stream>>>(Q, Mbuf, out);
}